// Round 1
// baseline (31.185 us; speedup 1.0000x reference)
//
#include <hip/hip_runtime.h>

// 3x3 median blur, BORDER_REPLICATE, NHWC float32.
// B=64, H=224, W=224, C=3  (compile-time constants for cheap addressing)

#define CSWAP(a,b) { float t_ = fminf(a,b); b = fmaxf(a,b); a = t_; }

__global__ __launch_bounds__(256) void median3x3_kernel(
    const float* __restrict__ in, float* __restrict__ out, int total)
{
    int idx = blockIdx.x * blockDim.x + threadIdx.x;
    if (idx >= total) return;

    const int C = 3, W = 224, H = 224;
    const int WC = W * C;

    int c  = idx % C;
    int t1 = idx / C;        // pixel index b*H*W + h*W + w
    int w  = t1 % W;
    int t2 = t1 / W;
    int h  = t2 % H;
    int b  = t2 / H;

    const float* img = in + (size_t)b * H * WC;

    int hm = (h > 0)     ? h - 1 : 0;
    int hp = (h < H - 1) ? h + 1 : H - 1;
    int wm = (w > 0)     ? w - 1 : 0;
    int wp = (w < W - 1) ? w + 1 : W - 1;

    const float* r0 = img + (size_t)hm * WC;
    const float* r1 = img + (size_t)h  * WC;
    const float* r2 = img + (size_t)hp * WC;

    int cm = wm * C + c;
    int cc = w  * C + c;
    int cp = wp * C + c;

    float p0 = r0[cm], p1 = r0[cc], p2 = r0[cp];
    float p3 = r1[cm], p4 = r1[cc], p5 = r1[cp];
    float p6 = r2[cm], p7 = r2[cc], p8 = r2[cp];

    // Paeth 19-exchange median-of-9 network; result lands in p4.
    CSWAP(p1,p2); CSWAP(p4,p5); CSWAP(p7,p8);
    CSWAP(p0,p1); CSWAP(p3,p4); CSWAP(p6,p7);
    CSWAP(p1,p2); CSWAP(p4,p5); CSWAP(p7,p8);
    CSWAP(p0,p3); CSWAP(p5,p8); CSWAP(p4,p7);
    CSWAP(p3,p6); CSWAP(p1,p4); CSWAP(p2,p5);
    CSWAP(p4,p7); CSWAP(p4,p2); CSWAP(p6,p4);
    CSWAP(p4,p2);

    out[idx] = p4;
}

extern "C" void kernel_launch(void* const* d_in, const int* in_sizes, int n_in,
                              void* d_out, int out_size, void* d_ws, size_t ws_size,
                              hipStream_t stream) {
    const float* x  = (const float*)d_in[0];
    float* out      = (float*)d_out;
    int total = out_size;  // 64*224*224*3 = 9,633,792

    int block = 256;
    int grid  = (total + block - 1) / block;
    median3x3_kernel<<<grid, block, 0, stream>>>(x, out, total);
}

// Round 2
// 24.375 us; speedup vs baseline: 1.2794x; 1.2794x over previous
//
#include <hip/hip_runtime.h>

// 3x3 median blur, BORDER_REPLICATE, NHWC float32. B=64, H=224, W=224, C=3.
// Vectorized: each thread produces 4 consecutive floats (one aligned float4)
// of one row. Row = 672 floats = 168 float4 chunks (exact).
//
// Median-of-9 via exact column decomposition:
//   sort each 3-high column (min3/med3/max3), then
//   median9 = med3( max3(col_mins), med3(col_meds), min3(col_maxs) )
// Column taps in NHWC are at float offsets -3, 0, +3 (same channel).
// Border replicate = substitute v[-3..-1]:=v[0..2] (row start) and
// v[4..6]:=v[1..3] (row end); rows clamp by pointer.

__device__ __forceinline__ float min3f(float a, float b, float c) {
    return fminf(fminf(a, b), c);           // fuses to v_min3_f32
}
__device__ __forceinline__ float max3f(float a, float b, float c) {
    return fmaxf(fmaxf(a, b), c);           // fuses to v_max3_f32
}
__device__ __forceinline__ float med3f(float a, float b, float c) {
    return __builtin_amdgcn_fmed3f(a, b, c); // v_med3_f32
}

__global__ __launch_bounds__(256) void median3x3_v4(
    const float* __restrict__ in, float* __restrict__ out)
{
    const int W = 224, H = 224, C = 3;
    const int ROWF   = W * C;      // 672 floats per row
    const int CHUNKS = ROWF / 4;   // 168 float4 chunks per row

    int t   = blockIdx.x * blockDim.x + threadIdx.x;  // exact grid, no tail
    int ci  = t % CHUNKS;
    int rid = t / CHUNKS;          // b*H + h
    int h   = rid % H;

    const float* rowC = in + (size_t)rid * ROWF;
    const float* rowU = rowC + ((h > 0)     ? -ROWF : 0);
    const float* rowD = rowC + ((h < H - 1) ?  ROWF : 0);

    const int li  = (ci > 0)          ? ci - 1 : 0;
    const int riq = (ci < CHUNKS - 1) ? ci + 1 : CHUNKS - 1;
    const bool first = (ci == 0), last = (ci == CHUNKS - 1);

    // v[r][q]: row r value at chunk-relative float position q-3 (q=0..9 -> -3..6)
    float v[3][10];
    const float* rows[3] = { rowU, rowC, rowD };
    #pragma unroll
    for (int r = 0; r < 3; ++r) {
        float4 L = ((const float4*)rows[r])[li];
        float4 M = ((const float4*)rows[r])[ci];
        float4 R = ((const float4*)rows[r])[riq];
        v[r][0] = first ? M.x : L.y;   // pos -3
        v[r][1] = first ? M.y : L.z;   // pos -2
        v[r][2] = first ? M.z : L.w;   // pos -1
        v[r][3] = M.x;
        v[r][4] = M.y;
        v[r][5] = M.z;
        v[r][6] = M.w;
        v[r][7] = last ? M.y : R.x;    // pos 4
        v[r][8] = last ? M.z : R.y;    // pos 5
        v[r][9] = last ? M.w : R.z;    // pos 6
    }

    // Per-column 3-element sort (shared across the 4 outputs)
    float lo[10], me[10], hi[10];
    #pragma unroll
    for (int q = 0; q < 10; ++q) {
        lo[q] = min3f(v[0][q], v[1][q], v[2][q]);
        me[q] = med3f(v[0][q], v[1][q], v[2][q]);
        hi[q] = max3f(v[0][q], v[1][q], v[2][q]);
    }

    // Output element j uses columns at positions j-3, j, j+3 -> q = j, j+3, j+6
    float o0, o1, o2, o3;
    {
        float a = max3f(lo[0], lo[3], lo[6]);
        float b = med3f(me[0], me[3], me[6]);
        float c = min3f(hi[0], hi[3], hi[6]);
        o0 = med3f(a, b, c);
    }
    {
        float a = max3f(lo[1], lo[4], lo[7]);
        float b = med3f(me[1], me[4], me[7]);
        float c = min3f(hi[1], hi[4], hi[7]);
        o1 = med3f(a, b, c);
    }
    {
        float a = max3f(lo[2], lo[5], lo[8]);
        float b = med3f(me[2], me[5], me[8]);
        float c = min3f(hi[2], hi[5], hi[8]);
        o2 = med3f(a, b, c);
    }
    {
        float a = max3f(lo[3], lo[6], lo[9]);
        float b = med3f(me[3], me[6], me[9]);
        float c = min3f(hi[3], hi[6], hi[9]);
        o3 = med3f(a, b, c);
    }

    ((float4*)(out + (size_t)rid * ROWF))[ci] = make_float4(o0, o1, o2, o3);
}

extern "C" void kernel_launch(void* const* d_in, const int* in_sizes, int n_in,
                              void* d_out, int out_size, void* d_ws, size_t ws_size,
                              hipStream_t stream) {
    const float* x = (const float*)d_in[0];
    float* out     = (float*)d_out;

    // total threads = 64 * 224 * 168 = 2,408,448 = 9408 * 256 (exact)
    const int total = 64 * 224 * 168;
    const int block = 256;
    const int grid  = total / block;
    median3x3_v4<<<grid, block, 0, stream>>>(x, out);
}

// Round 3
// 18.837 us; speedup vs baseline: 1.6555x; 1.2940x over previous
//
#include <hip/hip_runtime.h>

// 3x3 median blur, BORDER_REPLICATE, NHWC float32. B=64, H=224, W=224, C=3.
// Each thread produces 4 consecutive floats (one aligned float4) of one row.
// Row = 672 floats = 168 float4 chunks (exact).
//
// Median-of-9 via exact column decomposition (min3/med3/max3 single-inst).
// R2 change: chunked XCD-aware block swizzle. Default dispatch round-robins
// consecutive blocks across the 8 per-XCD L2s, so the 3x vertical row reuse
// missed L2 (each XCD re-fetched ~2.3x from HBM). Remapping blocks so each
// XCD owns a contiguous band of rows makes the reuse L2-local.
// grid = 9408 = 8 * 1176 exactly -> bijective swizzle.

__device__ __forceinline__ float min3f(float a, float b, float c) {
    return fminf(fminf(a, b), c);           // v_min3_f32
}
__device__ __forceinline__ float max3f(float a, float b, float c) {
    return fmaxf(fmaxf(a, b), c);           // v_max3_f32
}
__device__ __forceinline__ float med3f(float a, float b, float c) {
    return __builtin_amdgcn_fmed3f(a, b, c); // v_med3_f32
}

__global__ __launch_bounds__(256) void median3x3_v4(
    const float* __restrict__ in, float* __restrict__ out)
{
    const int W = 224, H = 224;
    const int ROWF   = W * 3;      // 672 floats per row
    const int CHUNKS = ROWF / 4;   // 168 float4 chunks per row
    const int NXCD = 8;
    const int BANDS = 9408 / NXCD; // 1176 blocks per XCD band

    // Chunked XCD swizzle: HW assigns block b to XCD b%8; give each XCD a
    // contiguous band of the row space.
    int bid  = blockIdx.x;
    int virt = (bid & (NXCD - 1)) * BANDS + (bid >> 3);

    int t   = virt * 256 + threadIdx.x;
    int ci  = t % CHUNKS;
    int rid = t / CHUNKS;          // b*H + h
    int h   = rid % H;

    const float* rowC = in + (size_t)rid * ROWF;
    const float* rowU = rowC + ((h > 0)     ? -ROWF : 0);
    const float* rowD = rowC + ((h < H - 1) ?  ROWF : 0);

    const int li  = (ci > 0)          ? ci - 1 : 0;
    const int riq = (ci < CHUNKS - 1) ? ci + 1 : CHUNKS - 1;
    const bool first = (ci == 0), last = (ci == CHUNKS - 1);

    // v[r][q]: row r value at chunk-relative float position q-3 (q=0..9 -> -3..6)
    float v[3][10];
    const float* rows[3] = { rowU, rowC, rowD };
    #pragma unroll
    for (int r = 0; r < 3; ++r) {
        float4 L = ((const float4*)rows[r])[li];
        float4 M = ((const float4*)rows[r])[ci];
        float4 R = ((const float4*)rows[r])[riq];
        v[r][0] = first ? M.x : L.y;   // pos -3
        v[r][1] = first ? M.y : L.z;   // pos -2
        v[r][2] = first ? M.z : L.w;   // pos -1
        v[r][3] = M.x;
        v[r][4] = M.y;
        v[r][5] = M.z;
        v[r][6] = M.w;
        v[r][7] = last ? M.y : R.x;    // pos 4
        v[r][8] = last ? M.z : R.y;    // pos 5
        v[r][9] = last ? M.w : R.z;    // pos 6
    }

    // Per-column 3-element sort (shared across the 4 outputs)
    float lo[10], me[10], hi[10];
    #pragma unroll
    for (int q = 0; q < 10; ++q) {
        lo[q] = min3f(v[0][q], v[1][q], v[2][q]);
        me[q] = med3f(v[0][q], v[1][q], v[2][q]);
        hi[q] = max3f(v[0][q], v[1][q], v[2][q]);
    }

    // Output element j uses columns at positions j-3, j, j+3 -> q = j, j+3, j+6
    float o0, o1, o2, o3;
    {
        float a = max3f(lo[0], lo[3], lo[6]);
        float b = med3f(me[0], me[3], me[6]);
        float c = min3f(hi[0], hi[3], hi[6]);
        o0 = med3f(a, b, c);
    }
    {
        float a = max3f(lo[1], lo[4], lo[7]);
        float b = med3f(me[1], me[4], me[7]);
        float c = min3f(hi[1], hi[4], hi[7]);
        o1 = med3f(a, b, c);
    }
    {
        float a = max3f(lo[2], lo[5], lo[8]);
        float b = med3f(me[2], me[5], me[8]);
        float c = min3f(hi[2], hi[5], hi[8]);
        o2 = med3f(a, b, c);
    }
    {
        float a = max3f(lo[3], lo[6], lo[9]);
        float b = med3f(me[3], me[6], me[9]);
        float c = min3f(hi[3], hi[6], hi[9]);
        o3 = med3f(a, b, c);
    }

    ((float4*)(out + (size_t)rid * ROWF))[ci] = make_float4(o0, o1, o2, o3);
}

extern "C" void kernel_launch(void* const* d_in, const int* in_sizes, int n_in,
                              void* d_out, int out_size, void* d_ws, size_t ws_size,
                              hipStream_t stream) {
    const float* x = (const float*)d_in[0];
    float* out     = (float*)d_out;

    // total threads = 64 * 224 * 168 = 2,408,448 = 9408 blocks * 256 (exact)
    const int grid  = 9408;
    const int block = 256;
    median3x3_v4<<<grid, block, 0, stream>>>(x, out);
}

// Round 4
// 18.341 us; speedup vs baseline: 1.7003x; 1.0271x over previous
//
#include <hip/hip_runtime.h>

// 3x3 median blur, BORDER_REPLICATE, NHWC float32. B=64, H=224, W=224, C=3.
// R3: vertical 4-row coarsening. Each thread produces the same float4 chunk
// for 4 consecutive rows of one image: 18 float4 loads (6 rows x L/M/R) +
// 4 float4 stores for 64 B of output -> 5.5 VMEM insts per output chunk
// (was 10). Column min3/med3/max3 sorts shared across the 4 row-windows.
// Grid = 2352 = 8 * 294; chunked XCD swizzle gives each XCD exactly 8 whole
// images -> all vertical reuse is XCD-local.

__device__ __forceinline__ float min3f(float a, float b, float c) {
    return fminf(fminf(a, b), c);           // v_min3_f32
}
__device__ __forceinline__ float max3f(float a, float b, float c) {
    return fmaxf(fmaxf(a, b), c);           // v_max3_f32
}
__device__ __forceinline__ float med3f(float a, float b, float c) {
    return __builtin_amdgcn_fmed3f(a, b, c); // v_med3_f32
}

__global__ __launch_bounds__(256) void median3x3_r4(
    const float* __restrict__ in, float* __restrict__ out)
{
    const int W = 224, H = 224;
    const int ROWF   = W * 3;      // 672 floats per row
    const int CHUNKS = ROWF / 4;   // 168 float4 chunks per row
    const int GROUPS = H / 4;      // 56 row-groups per image
    const int NXCD   = 8;
    const int BAND   = 2352 / NXCD; // 294 blocks per XCD band

    int bid  = blockIdx.x;
    int virt = (bid & (NXCD - 1)) * BAND + (bid >> 3);

    int t    = virt * 256 + threadIdx.x;
    int ci   = t % CHUNKS;
    int rest = t / CHUNKS;
    int g    = rest % GROUPS;      // row group within image
    int b    = rest / GROUPS;      // image index
    int r0   = g * 4;              // first output row of this thread

    const float* img = in + (size_t)b * H * ROWF;

    const int li  = (ci > 0)          ? ci - 1 : 0;
    const int riq = (ci < CHUNKS - 1) ? ci + 1 : CHUNKS - 1;
    const bool first = (ci == 0), last = (ci == CHUNKS - 1);

    // v[r][q]: input row (r0 + r - 1, clamped) at chunk-relative float
    // position q-3 (q = 0..9 -> -3..6)
    float v[6][10];
    #pragma unroll
    for (int r = 0; r < 6; ++r) {
        int h = r0 + r - 1;
        h = (h < 0) ? 0 : ((h > H - 1) ? H - 1 : h);
        const float4* rp = (const float4*)(img + (size_t)h * ROWF);
        float4 L = rp[li];
        float4 M = rp[ci];
        float4 R = rp[riq];
        v[r][0] = first ? M.x : L.y;   // pos -3
        v[r][1] = first ? M.y : L.z;   // pos -2
        v[r][2] = first ? M.z : L.w;   // pos -1
        v[r][3] = M.x;
        v[r][4] = M.y;
        v[r][5] = M.z;
        v[r][6] = M.w;
        v[r][7] = last ? M.y : R.x;    // pos 4
        v[r][8] = last ? M.z : R.y;    // pos 5
        v[r][9] = last ? M.w : R.z;    // pos 6
    }

    float* oimg = out + (size_t)b * H * ROWF;

    #pragma unroll
    for (int k = 0; k < 4; ++k) {      // output row r0 + k uses v[k..k+2]
        float lo[10], me[10], hi[10];
        #pragma unroll
        for (int q = 0; q < 10; ++q) {
            lo[q] = min3f(v[k][q], v[k + 1][q], v[k + 2][q]);
            me[q] = med3f(v[k][q], v[k + 1][q], v[k + 2][q]);
            hi[q] = max3f(v[k][q], v[k + 1][q], v[k + 2][q]);
        }
        float4 o;
        o.x = med3f(max3f(lo[0], lo[3], lo[6]),
                    med3f(me[0], me[3], me[6]),
                    min3f(hi[0], hi[3], hi[6]));
        o.y = med3f(max3f(lo[1], lo[4], lo[7]),
                    med3f(me[1], me[4], me[7]),
                    min3f(hi[1], hi[4], hi[7]));
        o.z = med3f(max3f(lo[2], lo[5], lo[8]),
                    med3f(me[2], me[5], me[8]),
                    min3f(hi[2], hi[5], hi[8]));
        o.w = med3f(max3f(lo[3], lo[6], lo[9]),
                    med3f(me[3], me[6], me[9]),
                    min3f(hi[3], hi[6], hi[9]));
        ((float4*)(oimg + (size_t)(r0 + k) * ROWF))[ci] = o;
    }
}

extern "C" void kernel_launch(void* const* d_in, const int* in_sizes, int n_in,
                              void* d_out, int out_size, void* d_ws, size_t ws_size,
                              hipStream_t stream) {
    const float* x = (const float*)d_in[0];
    float* out     = (float*)d_out;

    // total threads = 64 * 56 * 168 = 602,112 = 2352 blocks * 256 (exact)
    const int grid  = 2352;
    const int block = 256;
    median3x3_r4<<<grid, block, 0, stream>>>(x, out);
}

// Round 6
// 16.514 us; speedup vs baseline: 1.8884x; 1.1106x over previous
//
#include <hip/hip_runtime.h>

// 3x3 median blur, BORDER_REPLICATE, NHWC float32. B=64, H=224, W=224, C=3.
// R3: vertical 4-row coarsening (18 float4 loads + 4 stores per thread),
//     chunked XCD swizzle (grid 2352 = 8 * 294, band = 8 whole images).
// R5: nontemporal stores (via native ext_vector_type — HIP_vector_type is
//     rejected by the builtin). Output is never re-read; keeping stores out
//     of L2 stops write-allocation from evicting input rows before the
//     adjacent row-group re-reads them.

typedef float f32x4 __attribute__((ext_vector_type(4)));

__device__ __forceinline__ float min3f(float a, float b, float c) {
    return fminf(fminf(a, b), c);           // v_min3_f32
}
__device__ __forceinline__ float max3f(float a, float b, float c) {
    return fmaxf(fmaxf(a, b), c);           // v_max3_f32
}
__device__ __forceinline__ float med3f(float a, float b, float c) {
    return __builtin_amdgcn_fmed3f(a, b, c); // v_med3_f32
}

__global__ __launch_bounds__(256) void median3x3_r4(
    const float* __restrict__ in, float* __restrict__ out)
{
    const int W = 224, H = 224;
    const int ROWF   = W * 3;      // 672 floats per row
    const int CHUNKS = ROWF / 4;   // 168 float4 chunks per row
    const int GROUPS = H / 4;      // 56 row-groups per image
    const int NXCD   = 8;
    const int BAND   = 2352 / NXCD; // 294 blocks per XCD band

    int bid  = blockIdx.x;
    int virt = (bid & (NXCD - 1)) * BAND + (bid >> 3);

    int t    = virt * 256 + threadIdx.x;
    int ci   = t % CHUNKS;
    int rest = t / CHUNKS;
    int g    = rest % GROUPS;      // row group within image
    int b    = rest / GROUPS;      // image index
    int r0   = g * 4;              // first output row of this thread

    const float* img = in + (size_t)b * H * ROWF;

    const int li  = (ci > 0)          ? ci - 1 : 0;
    const int riq = (ci < CHUNKS - 1) ? ci + 1 : CHUNKS - 1;
    const bool first = (ci == 0), last = (ci == CHUNKS - 1);

    // v[r][q]: input row (r0 + r - 1, clamped) at chunk-relative float
    // position q-3 (q = 0..9 -> -3..6)
    float v[6][10];
    #pragma unroll
    for (int r = 0; r < 6; ++r) {
        int h = r0 + r - 1;
        h = (h < 0) ? 0 : ((h > H - 1) ? H - 1 : h);
        const float4* rp = (const float4*)(img + (size_t)h * ROWF);
        float4 L = rp[li];
        float4 M = rp[ci];
        float4 R = rp[riq];
        v[r][0] = first ? M.x : L.y;   // pos -3
        v[r][1] = first ? M.y : L.z;   // pos -2
        v[r][2] = first ? M.z : L.w;   // pos -1
        v[r][3] = M.x;
        v[r][4] = M.y;
        v[r][5] = M.z;
        v[r][6] = M.w;
        v[r][7] = last ? M.y : R.x;    // pos 4
        v[r][8] = last ? M.z : R.y;    // pos 5
        v[r][9] = last ? M.w : R.z;    // pos 6
    }

    float* oimg = out + (size_t)b * H * ROWF;

    #pragma unroll
    for (int k = 0; k < 4; ++k) {      // output row r0 + k uses v[k..k+2]
        float lo[10], me[10], hi[10];
        #pragma unroll
        for (int q = 0; q < 10; ++q) {
            lo[q] = min3f(v[k][q], v[k + 1][q], v[k + 2][q]);
            me[q] = med3f(v[k][q], v[k + 1][q], v[k + 2][q]);
            hi[q] = max3f(v[k][q], v[k + 1][q], v[k + 2][q]);
        }
        f32x4 o;
        o.x = med3f(max3f(lo[0], lo[3], lo[6]),
                    med3f(me[0], me[3], me[6]),
                    min3f(hi[0], hi[3], hi[6]));
        o.y = med3f(max3f(lo[1], lo[4], lo[7]),
                    med3f(me[1], me[4], me[7]),
                    min3f(hi[1], hi[4], hi[7]));
        o.z = med3f(max3f(lo[2], lo[5], lo[8]),
                    med3f(me[2], me[5], me[8]),
                    min3f(hi[2], hi[5], hi[8]));
        o.w = med3f(max3f(lo[3], lo[6], lo[9]),
                    med3f(me[3], me[6], me[9]),
                    min3f(hi[3], hi[6], hi[9]));
        // Nontemporal: bypass L2 allocation for the write stream.
        f32x4* dst = (f32x4*)(oimg + (size_t)(r0 + k) * ROWF) + ci;
        __builtin_nontemporal_store(o, dst);
    }
}

extern "C" void kernel_launch(void* const* d_in, const int* in_sizes, int n_in,
                              void* d_out, int out_size, void* d_ws, size_t ws_size,
                              hipStream_t stream) {
    const float* x = (const float*)d_in[0];
    float* out     = (float*)d_out;

    // total threads = 64 * 56 * 168 = 602,112 = 2352 blocks * 256 (exact)
    const int grid  = 2352;
    const int block = 256;
    median3x3_r4<<<grid, block, 0, stream>>>(x, out);
}